// Round 11
// baseline (424428.271 us; speedup 1.0000x reference)
//
#include <hip/hip_runtime.h>
#include <math.h>

// ControlledNODE: sequential RK4 scan, T=65536 steps.
// Round-11 = round-10 skeleton with ONE cross-wave barrier per stage:
//  * L2 split-K partial exchange (pex) stays the only cross-wave sync.
//  * L3 now FULL-K per wave: z2 is replicated per wave (z2slot), lane
//    (m, kh=l>>5) covers 64 slots with w3p[32] (64 floats), one
//    shfl_xor(32) completes drift -> pb2 + its barrier + round-trip gone.
//  * pex double-buffered by stage parity: cross-stage WAR separated by
//    barriers, no timing assumptions.
//  * Register budget: W1 u-part (8 floats, once/step) -> LDS upart[8][128]
//    (lane-stride-1, conflict-free); weights = 32+128+64 = 224 floats.
// Per stage: 1 wg_barrier + 3 free wave_barriers. 4 s_barriers/step vs 8.

constexpr int T_STEPS = 65536;
constexpr int HD  = 32;   // state dim
constexpr int HID = 128;  // hidden dim

typedef float v2f __attribute__((ext_vector_type(2)));

__device__ __forceinline__ v2f fma2(v2f a, v2f b, v2f c) {
    return __builtin_elementwise_fma(a, b, c);   // -> v_pk_fma_f32
}

__device__ __forceinline__ float silu_f(float a) {
    // a * sigmoid(a); exp overflow -> inf -> a/inf = 0 (correct limit)
    return a / (1.0f + __expf(-a));
}

// Workgroup barrier without vmcnt drain.
__device__ __forceinline__ void wg_barrier() {
    asm volatile("s_waitcnt lgkmcnt(0)" ::: "memory");
    __builtin_amdgcn_s_barrier();
    asm volatile("" ::: "memory");
}

__global__ __launch_bounds__(128, 1)
void node_scan(const float* __restrict__ U,
               const float* __restrict__ h0,
               const float* __restrict__ W1, const float* __restrict__ b1,
               const float* __restrict__ W2, const float* __restrict__ b2,
               const float* __restrict__ W3, const float* __restrict__ b3,
               const float* __restrict__ Wd, const float* __restrict__ bd,
               const float* __restrict__ Wt, const float* __restrict__ bt,
               const float* __restrict__ Wc, const float* __restrict__ bc,
               float* __restrict__ out)
{
    const int tid = threadIdx.x;    // 0..127
    const int j   = tid;            // L1 output unit
    const int l   = tid & 63;       // lane within wave; L2 outputs l, l+64
    const int m   = tid & 31;       // state/drift index
    const int kh  = (tid >> 5) & 1; // L3 K-half within wave (l>>5)
    const int wv  = tid >> 6;       // wave id 0/1; L2 K-half base = wv*64

    __shared__ __align__(16) float xbuf[HD];       // RK-stage state input
    __shared__ __align__(16) float z1buf[HID];     // unit order
    __shared__ __align__(16) float z2slot[HID];    // slot 2l=unit l, 2l+1=unit l+64
    __shared__ __align__(16) float pexbuf[2][2 * HID]; // L2 partials, dbuf by parity
    __shared__ __align__(16) float upart[8 * HID]; // W1 u-part, row-major

    // ---- one-time: W1 u-part into LDS (own column; own-write/own-read) ----
#pragma unroll
    for (int i = 0; i < 8; ++i) upart[i * HID + j] = W1[(32 + i) * HID + j];

    // ---- one-time: weights into registers as packed pairs ----
    v2f w1p[16];                                  // x part only
#pragma unroll
    for (int i = 0; i < 16; ++i) {
        w1p[i].x = W1[(2 * i) * HID + j];
        w1p[i].y = W1[(2 * i + 1) * HID + j];
    }
    const float b1r = b1[j];

    // W2 slices for outputs l and l+64 over K-half [wv*64, wv*64+64)
    v2f w2a[32], w2b[32];
#pragma unroll
    for (int kp = 0; kp < 32; ++kp) {
        const int k = wv * 64 + 2 * kp;
        w2a[kp].x = W2[k * HID + l];
        w2a[kp].y = W2[(k + 1) * HID + l];
        w2b[kp].x = W2[k * HID + l + 64];
        w2b[kp].y = W2[(k + 1) * HID + l + 64];
    }
    const float b2a = b2[l], b2b = b2[l + 64];

    // W3 full half per lane, SLOT order: w3p[i] covers slots kh*64+2i, +2i+1
    // slot s -> unit (s>>1) + (s&1)*64  =>  units kh*32+i and kh*32+i+64
    v2f w3p[32];
#pragma unroll
    for (int i = 0; i < 32; ++i) {
        w3p[i].x = W3[(kh * 32 + i) * HD + m];
        w3p[i].y = W3[(kh * 32 + i + 64) * HD + m];
    }
    const float b3r = b3[m];

    // heads: wave0 reduces d and c, wave1 reduces t
    const float whr = (wv == 0) ? Wd[m] : Wt[m];
    const float wcr = Wc[m];
    const float bd0 = bd[0], bt0 = bt[0], bc0 = bc[0];

    float hm   = h0[m];    // replicated in all 128 lanes
    float xm   = hm;       // current stage input state x[m]
    float kacc = 0.0f;

    const float DT  = 5.0f / 60.0f;
    const float HDT = 0.5f * DT;
    const float W6  = DT / 6.0f;

    // u double-buffer (same addr all lanes -> broadcast, L2-cached)
    float4 ua = *(const float4*)(U);
    float4 ub = *(const float4*)(U + 4);

    xbuf[m] = xm;                    // all lanes, identical values: benign
    wg_barrier();

    for (int t = 0; t < T_STEPS; ++t) {
        // prefetch next step's u (no vmcnt drain at barriers -> in flight)
        const int tn = (t + 1 < T_STEPS) ? (t + 1) : t;
        const float4 na = *(const float4*)(U + tn * 8);
        const float4 nb = *(const float4*)(U + tn * 8 + 4);

        // ---- heads from current h (pre-update): pure reg + shuffle ----
        {
            float p  = hm * whr;
            float pc = hm * wcr;
            p += __shfl_xor(p, 16);  pc += __shfl_xor(pc, 16);
            p += __shfl_xor(p, 8);   pc += __shfl_xor(pc, 8);
            p += __shfl_xor(p, 4);   pc += __shfl_xor(pc, 4);
            p += __shfl_xor(p, 2);   pc += __shfl_xor(pc, 2);
            p += __shfl_xor(p, 1);   pc += __shfl_xor(pc, 1);
            if (tid == 0)  { out[t] = p + bd0; out[2 * T_STEPS + t] = pc + bc0; }
            if (tid == 64) { out[T_STEPS + t] = p + bt0; }
        }

        // ---- u-projection (once/step): weights from LDS, conflict-free ----
        float upj = b1r;
        {
            const float uu[8] = {ua.x, ua.y, ua.z, ua.w, ub.x, ub.y, ub.z, ub.w};
#pragma unroll
            for (int i = 0; i < 8; ++i)
                upj = fmaf(uu[i], upart[i * HID + j], upj);
        }

#pragma unroll
        for (int st = 0; st < 4; ++st) {
            const int p = st & 1;    // pex parity buffer

            // ---- L1: z1[j] = silu([x,u] @ W1 + b1), packed ----
            v2f a0 = {upj, 0.0f}, a1 = {0.0f, 0.0f};
            const float4* xv = (const float4*)xbuf;
#pragma unroll
            for (int i4 = 0; i4 < 8; ++i4) {
                const float4 v = xv[i4];            // broadcast read
                v2f lo; lo.x = v.x; lo.y = v.y;
                v2f hi; hi.x = v.z; hi.y = v.w;
                a0 = fma2(lo, w1p[2 * i4],     a0);
                a1 = fma2(hi, w1p[2 * i4 + 1], a1);
            }
            const v2f as = a0 + a1;
            z1buf[j] = silu_f(as.x + as.y);
            __builtin_amdgcn_wave_barrier();         // own z1 half < own reads

            // ---- L2 split-K: outputs (l, l+64) over own wave's z1 half ----
            v2f aA0 = {0.0f, 0.0f}, aA1 = {0.0f, 0.0f};
            v2f aB0 = {0.0f, 0.0f}, aB1 = {0.0f, 0.0f};
            const float4* z1v = (const float4*)(z1buf + wv * 64);
#pragma unroll
            for (int i4 = 0; i4 < 16; ++i4) {
                const float4 v = z1v[i4];           // broadcast read (own half)
                v2f lo; lo.x = v.x; lo.y = v.y;
                v2f hi; hi.x = v.z; hi.y = v.w;
                aA0 = fma2(lo, w2a[2 * i4],     aA0);
                aA1 = fma2(hi, w2a[2 * i4 + 1], aA1);
                aB0 = fma2(lo, w2b[2 * i4],     aB0);
                aB1 = fma2(hi, w2b[2 * i4 + 1], aB1);
            }
            const v2f sA = aA0 + aA1;
            const v2f sB = aB0 + aB1;
            float2 mine;
            mine.x = sA.x + sA.y;                   // partial for output l
            mine.y = sB.x + sB.y;                   // partial for output l+64
            ((float2*)pexbuf[p])[wv * 64 + l] = mine;
            wg_barrier();                            // THE stage barrier

            const float2 po = ((const float2*)pexbuf[p])[(1 ^ wv) * 64 + l];
            const float z2A = silu_f(mine.x + po.x + b2a);
            const float z2B = silu_f(mine.y + po.y + b2b);
            float2 zs; zs.x = z2A; zs.y = z2B;
            ((float2*)z2slot)[l] = zs;              // full copy per wave: benign
            __builtin_amdgcn_wave_barrier();         // own z2 writes < own reads

            // ---- L3 FULL-K per wave: drift[m] over slots [kh*64, kh*64+64) ----
            v2f p0 = {0.0f, 0.0f}, p1 = {0.0f, 0.0f};
            v2f p2 = {0.0f, 0.0f}, p3 = {0.0f, 0.0f};
            const float4* z2v = (const float4*)(z2slot + kh * 64);
#pragma unroll
            for (int i4 = 0; i4 < 16; ++i4) {
                const float4 v = z2v[i4];           // 2 addr groups: free
                v2f lo; lo.x = v.x; lo.y = v.y;
                v2f hi; hi.x = v.z; hi.y = v.w;
                if (i4 & 1) {
                    p2 = fma2(lo, w3p[2 * i4],     p2);
                    p3 = fma2(hi, w3p[2 * i4 + 1], p3);
                } else {
                    p0 = fma2(lo, w3p[2 * i4],     p0);
                    p1 = fma2(hi, w3p[2 * i4 + 1], p1);
                }
            }
            const v2f ps = (p0 + p1) + (p2 + p3);
            float pr = ps.x + ps.y;
            pr += __shfl_xor(pr, 32);   // combine kh halves within wave
            const float drift = pr + b3r;

            // ---- RK combine: ALL lanes redundantly (drift replicated) ----
            const float k = 0.02f * drift - 0.1f * xm;
            if (st == 0)      { kacc = k;           xm = hm + HDT * k; }
            else if (st == 1) { kacc += 2.0f * k;   xm = hm + HDT * k; }
            else if (st == 2) { kacc += 2.0f * k;   xm = hm + DT  * k; }
            else {
                kacc += k;
                float hn = hm + W6 * kacc;
                if (!isfinite(hn)) hn = 0.0f;        // nan_to_num BEFORE tanh
                hn = tanhf(hn);
                hn = fminf(fmaxf(hn, -5.0f), 5.0f);  // fidelity no-op after tanh
                hm = hn; xm = hn;
            }
            xbuf[m] = xm;   // all lanes, identical values: benign race
            __builtin_amdgcn_wave_barrier();         // wave-local: xbuf -> L1
        }
        ua = na; ub = nb;
    }

    if (tid < HD) out[3 * T_STEPS + tid] = hm;
}

extern "C" void kernel_launch(void* const* d_in, const int* in_sizes, int n_in,
                              void* d_out, int out_size, void* d_ws, size_t ws_size,
                              hipStream_t stream) {
    const float* U  = (const float*)d_in[0];
    const float* h0 = (const float*)d_in[1];
    const float* W1 = (const float*)d_in[2];
    const float* b1 = (const float*)d_in[3];
    const float* W2 = (const float*)d_in[4];
    const float* b2 = (const float*)d_in[5];
    const float* W3 = (const float*)d_in[6];
    const float* b3 = (const float*)d_in[7];
    const float* Wd = (const float*)d_in[8];
    const float* bd = (const float*)d_in[9];
    const float* Wt = (const float*)d_in[10];
    const float* bt = (const float*)d_in[11];
    const float* Wc = (const float*)d_in[12];
    const float* bc = (const float*)d_in[13];
    float* out = (float*)d_out;

    node_scan<<<1, 128, 0, stream>>>(U, h0, W1, b1, W2, b2, W3, b3,
                                     Wd, bd, Wt, bt, Wc, bc, out);
}

// Round 12
// 222341.846 us; speedup vs baseline: 1.9089x; 1.9089x over previous
//
#include <hip/hip_runtime.h>
#include <math.h>

// ControlledNODE: sequential RK4 scan, T=65536 steps.
// Round-12: 256 threads = 4 waves (1/SIMD). Per-lane weights drop to 136
// floats (W1 40 + W2 64 + W3 32) -> fully arch-VGPR-resident: kills the
// AGPR-parking churn (rounds 2/6/11 proved the ~200-float cliff at 128 thr)
// AND halves per-lane FMA issue. Still 2 cross-wave barriers/stage.
// Wave w = (wk = w&1: z1-half produced = L2 K-half; wo = w>>1: output half).
// All other LDS producer->consumer edges are wave-local in-order DS
// (each wave reads only ranges it wrote itself; replicated writes carry
// identical values -> benign races). Validated pattern from r7-r10.

constexpr int T_STEPS = 65536;
constexpr int HD  = 32;   // state dim
constexpr int HID = 128;  // hidden dim

typedef float v2f __attribute__((ext_vector_type(2)));

__device__ __forceinline__ v2f fma2(v2f a, v2f b, v2f c) {
    return __builtin_elementwise_fma(a, b, c);   // -> v_pk_fma_f32
}

__device__ __forceinline__ float silu_f(float a) {
    // a * sigmoid(a); exp overflow -> inf -> a/inf = 0 (correct limit)
    return a / (1.0f + __expf(-a));
}

// Workgroup barrier without vmcnt drain.
__device__ __forceinline__ void wg_barrier() {
    asm volatile("s_waitcnt lgkmcnt(0)" ::: "memory");
    __builtin_amdgcn_s_barrier();
    asm volatile("" ::: "memory");
}

__global__ __launch_bounds__(256, 1)
void node_scan(const float* __restrict__ U,
               const float* __restrict__ h0,
               const float* __restrict__ W1, const float* __restrict__ b1,
               const float* __restrict__ W2, const float* __restrict__ b2,
               const float* __restrict__ W3, const float* __restrict__ b3,
               const float* __restrict__ Wd, const float* __restrict__ bd,
               const float* __restrict__ Wt, const float* __restrict__ bt,
               const float* __restrict__ Wc, const float* __restrict__ bc,
               float* __restrict__ out)
{
    const int tid = threadIdx.x;    // 0..255
    const int lam = tid & 63;       // lane within wave
    const int w   = tid >> 6;       // wave 0..3
    const int wk  = w & 1;          // z1 half produced == L2 K-half
    const int wo  = w >> 1;         // L2/L3 output half
    const int j1  = lam + wk * 64;  // L1 output unit
    const int o   = lam + wo * 64;  // L2 output unit
    const int m   = tid & 31;       // state/drift index
    const int sub = (tid >> 5) & 1; // L3 sub-split within wave

    __shared__ __align__(16) float xbuf[HD];      // RK-stage state input
    __shared__ __align__(16) float z1buf[HID];    // unit order
    __shared__ __align__(16) float z2buf[HID];    // unit order
    __shared__ __align__(16) float pex[2 * HID];  // L2 K-half partials
    __shared__ __align__(16) float pdrift[64];    // L3 half partials

    // ---- one-time: weights into registers as packed pairs ----
    v2f w1p[20];                                  // rows 0..31 = x, 32..39 = u
#pragma unroll
    for (int i = 0; i < 20; ++i) {
        w1p[i].x = W1[(2 * i) * HID + j1];
        w1p[i].y = W1[(2 * i + 1) * HID + j1];
    }
    const float b1r = b1[j1];

    // W2 column o over K-half [wk*64, wk*64+64)
    v2f w2p[32];
#pragma unroll
    for (int kp = 0; kp < 32; ++kp) {
        const int k = wk * 64 + 2 * kp;
        w2p[kp].x = W2[k * HID + o];
        w2p[kp].y = W2[(k + 1) * HID + o];
    }
    const float b2r = b2[o];

    // W3: drift[m] partial over z2 units [wo*64 + sub*32, +32)
    v2f w3p[16];
#pragma unroll
    for (int i = 0; i < 16; ++i) {
        const int u0 = wo * 64 + sub * 32 + 2 * i;
        w3p[i].x = W3[u0 * HD + m];
        w3p[i].y = W3[(u0 + 1) * HD + m];
    }
    const float b3r = b3[m];

    // heads: wave0 -> d, wave1 -> t, wave2 -> c, wave3 idle
    const float whr = (w == 0) ? Wd[m] : (w == 1) ? Wt[m] : (w == 2) ? Wc[m] : 0.0f;
    const float bh  = (w == 0) ? bd[0] : (w == 1) ? bt[0] : (w == 2) ? bc[0] : 0.0f;

    float hm   = h0[m];    // replicated in all 256 lanes
    float xm   = hm;       // current stage input state x[m]
    float kacc = 0.0f;

    const float DT  = 5.0f / 60.0f;
    const float HDT = 0.5f * DT;
    const float W6  = DT / 6.0f;

    // u double-buffer (same addr all lanes -> broadcast, L2-cached)
    float4 ua = *(const float4*)(U);
    float4 ub = *(const float4*)(U + 4);

    xbuf[m] = xm;                    // all lanes, identical values: benign
    wg_barrier();

    for (int t = 0; t < T_STEPS; ++t) {
        // prefetch next step's u (no vmcnt drain at barriers -> in flight)
        const int tn = (t + 1 < T_STEPS) ? (t + 1) : t;
        const float4 na = *(const float4*)(U + tn * 8);
        const float4 nb = *(const float4*)(U + tn * 8 + 4);

        // ---- heads from current h (pre-update): one head per wave ----
        {
            float p = hm * whr;
            p += __shfl_xor(p, 16);
            p += __shfl_xor(p, 8);
            p += __shfl_xor(p, 4);
            p += __shfl_xor(p, 2);
            p += __shfl_xor(p, 1);
            if (lam == 0 && w < 3) out[w * T_STEPS + t] = p + bh;
        }

        // ---- u-projection: constant across the 4 RK stages, hoisted ----
        float upj;
        {
            v2f u0; u0.x = ua.x; u0.y = ua.y;
            v2f u1; u1.x = ua.z; u1.y = ua.w;
            v2f u2; u2.x = ub.x; u2.y = ub.y;
            v2f u3; u3.x = ub.z; u3.y = ub.w;
            v2f up = {b1r, 0.0f};
            up = fma2(u0, w1p[16], up);
            up = fma2(u1, w1p[17], up);
            up = fma2(u2, w1p[18], up);
            up = fma2(u3, w1p[19], up);
            upj = up.x + up.y;
        }

#pragma unroll
        for (int st = 0; st < 4; ++st) {
            // ---- L1: z1[j1] = silu([x,u] @ W1 + b1) (replicated x2) ----
            v2f a0 = {upj, 0.0f}, a1 = {0.0f, 0.0f};
            const float4* xv = (const float4*)xbuf;
#pragma unroll
            for (int i4 = 0; i4 < 8; ++i4) {
                const float4 v = xv[i4];            // broadcast read (own writes)
                v2f lo; lo.x = v.x; lo.y = v.y;
                v2f hi; hi.x = v.z; hi.y = v.w;
                a0 = fma2(lo, w1p[2 * i4],     a0);
                a1 = fma2(hi, w1p[2 * i4 + 1], a1);
            }
            const v2f as = a0 + a1;
            z1buf[j1] = silu_f(as.x + as.y);        // waves (0,2) half0, (1,3) half1
            __builtin_amdgcn_wave_barrier();         // own z1 half < own reads

            // ---- L2: output o over own K-half [wk*64, +64) ----
            v2f c0 = {0.0f, 0.0f}, c1 = {0.0f, 0.0f};
            const float4* z1v = (const float4*)(z1buf + wk * 64);
#pragma unroll
            for (int i4 = 0; i4 < 16; ++i4) {
                const float4 v = z1v[i4];           // broadcast read (own half)
                v2f lo; lo.x = v.x; lo.y = v.y;
                v2f hi; hi.x = v.z; hi.y = v.w;
                c0 = fma2(lo, w2p[2 * i4],     c0);
                c1 = fma2(hi, w2p[2 * i4 + 1], c1);
            }
            const v2f cs = c0 + c1;
            const float mine = cs.x + cs.y;         // K-half partial for unit o
            pex[wk * HID + o] = mine;
            wg_barrier();                            // BARRIER-A: pex exchange

            const float po = pex[(1 ^ wk) * HID + o];
            const float z2 = silu_f(mine + po + b2r);
            z2buf[o] = z2;                           // waves (0,1) half0, (2,3) half1
            __builtin_amdgcn_wave_barrier();         // own z2 half < own reads

            // ---- L3 partial: drift[m] over own z2 half, sub-split ----
            v2f p0 = {0.0f, 0.0f}, p1 = {0.0f, 0.0f};
            const float4* z2v = (const float4*)(z2buf + wo * 64 + sub * 32);
#pragma unroll
            for (int i4 = 0; i4 < 8; ++i4) {
                const float4 v = z2v[i4];           // 2 addr groups: free
                v2f lo; lo.x = v.x; lo.y = v.y;
                v2f hi; hi.x = v.z; hi.y = v.w;
                p0 = fma2(lo, w3p[2 * i4],     p0);
                p1 = fma2(hi, w3p[2 * i4 + 1], p1);
            }
            const v2f ps = p0 + p1;
            float pr = ps.x + ps.y;
            pr += __shfl_xor(pr, 32);   // combine sub halves within wave
            pdrift[wo * 32 + m] = pr;   // 2 waves/half identical: benign
            wg_barrier();                            // BARRIER-B: drift exchange

            // ---- RK combine: ALL lanes redundantly (hm replicated) ----
            {
                const float drift = (pdrift[m] + pdrift[m + 32]) + b3r;
                const float k = 0.02f * drift - 0.1f * xm;
                if (st == 0)      { kacc = k;           xm = hm + HDT * k; }
                else if (st == 1) { kacc += 2.0f * k;   xm = hm + HDT * k; }
                else if (st == 2) { kacc += 2.0f * k;   xm = hm + DT  * k; }
                else {
                    kacc += k;
                    float hn = hm + W6 * kacc;
                    if (!isfinite(hn)) hn = 0.0f;        // nan_to_num BEFORE tanh
                    hn = tanhf(hn);
                    hn = fminf(fmaxf(hn, -5.0f), 5.0f);  // fidelity no-op after tanh
                    hm = hn; xm = hn;
                }
                xbuf[m] = xm;   // all lanes, identical values: benign race
            }
            __builtin_amdgcn_wave_barrier();         // wave-local: xbuf -> L1
        }
        ua = na; ub = nb;
    }

    if (tid < HD) out[3 * T_STEPS + tid] = hm;
}

extern "C" void kernel_launch(void* const* d_in, const int* in_sizes, int n_in,
                              void* d_out, int out_size, void* d_ws, size_t ws_size,
                              hipStream_t stream) {
    const float* U  = (const float*)d_in[0];
    const float* h0 = (const float*)d_in[1];
    const float* W1 = (const float*)d_in[2];
    const float* b1 = (const float*)d_in[3];
    const float* W2 = (const float*)d_in[4];
    const float* b2 = (const float*)d_in[5];
    const float* W3 = (const float*)d_in[6];
    const float* b3 = (const float*)d_in[7];
    const float* Wd = (const float*)d_in[8];
    const float* bd = (const float*)d_in[9];
    const float* Wt = (const float*)d_in[10];
    const float* bt = (const float*)d_in[11];
    const float* Wc = (const float*)d_in[12];
    const float* bc = (const float*)d_in[13];
    float* out = (float*)d_out;

    node_scan<<<1, 256, 0, stream>>>(U, h0, W1, b1, W2, b2, W3, b3,
                                     Wd, bd, Wt, bt, Wc, bc, out);
}